// Round 6
// baseline (294.522 us; speedup 1.0000x reference)
//
#include <hip/hip_runtime.h>
#include <hip/hip_bf16.h>

// Problem constants
#define BATCH 32
#define NNODE 4096
#define CIN 32
#define COUT 64
#define KDEG 5
#define POOL 4
#define NNZ_E 65536
#define BC (BATCH * CIN)         // 1024 elems per node-row
#define TBF ((size_t)NNODE * BC) // elems per Chebyshev level (bf16 storage)

typedef short s16x8 __attribute__((ext_vector_type(8)));
typedef float f32x4 __attribute__((ext_vector_type(4)));
typedef unsigned long long u64;

// float -> bf16 bits, round-to-nearest-even
__device__ __forceinline__ unsigned short f2bf(float f) {
    union { float f; unsigned int u; } v; v.f = f;
    unsigned int u = v.u;
    u += 0x7fffu + ((u >> 16) & 1u);
    return (unsigned short)(u >> 16);
}
__device__ __forceinline__ float bf2f(unsigned short b) {
    union { float f; unsigned int u; } v; v.u = ((unsigned int)b) << 16;
    return v.f;
}
__device__ __forceinline__ u64 pack4(float a, float b, float c, float d) {
    return (u64)f2bf(a) | ((u64)f2bf(b) << 16) | ((u64)f2bf(c) << 32) | ((u64)f2bf(d) << 48);
}

// ---------------- prep: transpose x -> t0 (bf16), pack W ----------------

__global__ void prep_kernel(const float* __restrict__ x, unsigned short* __restrict__ t0,
                            const float* __restrict__ W, unsigned short* __restrict__ WB) {
    int idx = blockIdx.x * 256 + threadIdx.x;   // [0, 1048576)
    int n   = idx >> 8;
    int rem = idx & 255;
    int b   = rem >> 3;
    int c4  = rem & 7;
    float4 v = ((const float4*)x)[(b * NNODE + n) * 8 + c4];
    ((u64*)t0)[idx] = pack4(v.x, v.y, v.z, v.w);

    if (idx < KDEG * COUT * CIN) {
        int c = idx & 31;
        int rest = idx >> 5;
        int o = rest & 63;
        int k = rest >> 6;
        // WB[k][o][c] : B-fragment order for mfma_16x16x32 (lane nn=o, kk=c)
        WB[idx] = f2bf(W[(c * KDEG + k) * COUT + o]);
    }
}

// ---------------- CSR build in ONE kernel: LDS hist + scan + scatter ----------------

__global__ __launch_bounds__(1024) void csr_build_kernel(
        const int* __restrict__ erow, const int* __restrict__ ecol,
        const float* __restrict__ eval, int2* __restrict__ es,
        int* __restrict__ row_start) {
    __shared__ int hist[NNODE];     // 16 KB
    __shared__ int wpart[16];
    int tid = threadIdx.x;
#pragma unroll
    for (int j = 0; j < 4; j++) hist[tid * 4 + j] = 0;
    __syncthreads();
    for (int e = tid; e < NNZ_E; e += 1024) atomicAdd(&hist[erow[e]], 1);
    __syncthreads();

    int v0 = hist[tid * 4], v1 = hist[tid * 4 + 1], v2 = hist[tid * 4 + 2], v3 = hist[tid * 4 + 3];
    int s = v0 + v1 + v2 + v3;
    int lane = tid & 63;
    int wid  = tid >> 6;
    int incl = s;
    for (int off = 1; off < 64; off <<= 1) {
        int t = __shfl_up(incl, off);
        if (lane >= off) incl += t;
    }
    if (lane == 63) wpart[wid] = incl;
    __syncthreads();
    if (wid == 0) {
        int x = (lane < 16) ? wpart[lane] : 0;
        for (int off = 1; off < 16; off <<= 1) {
            int t = __shfl_up(x, off);
            if (lane >= off) x += t;
        }
        if (lane < 16) wpart[lane] = x;   // inclusive wave sums
    }
    __syncthreads();
    int wbase = (wid == 0) ? 0 : wpart[wid - 1];
    int excl = wbase + incl - s;
    int p0 = excl, p1 = p0 + v0, p2 = p1 + v1, p3 = p2 + v2;
    row_start[tid * 4]     = p0;
    row_start[tid * 4 + 1] = p1;
    row_start[tid * 4 + 2] = p2;
    row_start[tid * 4 + 3] = p3;
    if (tid == 1023) row_start[NNODE] = NNZ_E;
    hist[tid * 4] = p0; hist[tid * 4 + 1] = p1;
    hist[tid * 4 + 2] = p2; hist[tid * 4 + 3] = p3;
    __syncthreads();
    for (int e = tid; e < NNZ_E; e += 1024) {
        int r = erow[e];
        int pos = atomicAdd(&hist[r], 1);
        es[pos] = make_int2(ecol[e], __float_as_int(eval[e]));
    }
}

// ---------------- strip-mined column-sliced bf16 SpMM: out = scale*(L@in) - sub ----
// Wave = (slice, 4-row strip). Slice = 128 cols (1 MB) pinned to XCD via blockIdx&7.
// Per row: sub prefetched first (hidden), 16 edges/iter (2 ep-groups x 8-deep).
// Prologue (row_start) amortized over 4 rows. Normal out-store keeps slice in L2.

__global__ __launch_bounds__(256) void spmm_cheb_strip_kernel(
        const unsigned short* __restrict__ in, const unsigned short* __restrict__ sub,
        unsigned short* __restrict__ out, float scale, int has_sub,
        const int* __restrict__ row_start, const int2* __restrict__ es) {
    int bx    = blockIdx.x;            // [0, 2048)
    int slice = bx & 7;                // XCD-matched column slice
    int w     = threadIdx.x >> 6;
    int strip = (bx >> 3) * 4 + w;     // [0, 1024)
    int r0    = strip * 4;
    int lane  = threadIdx.x & 63;
    int ep    = lane >> 5;             // edge-parallel half 0..1
    int c     = lane & 31;             // u64 col within slice
    int sc    = slice * 32 + c;        // absolute u64 col (256 per row)

    const u64* in8 = (const u64*)in;

    int rs[5];
#pragma unroll
    for (int j = 0; j < 5; j++) rs[j] = row_start[r0 + j];

#pragma unroll
    for (int rr = 0; rr < 4; rr++) {
        int r = r0 + rr;
        int beg = rs[rr], end = rs[rr + 1];
        size_t oi = (size_t)r * 256 + sc;
        u64 sv = 0;
        if (has_sub) sv = __builtin_nontemporal_load((const u64*)sub + oi);  // early

        float4 a0 = make_float4(0.f, 0.f, 0.f, 0.f);
        float4 a1 = a0;

        for (int base = beg + ep; base < end; base += 16) {
            float vv[8];
            u64   xx[8];
#pragma unroll
            for (int j = 0; j < 8; j++) {
                int idx = base + 2 * j;
                int src = idx < end ? idx : beg;   // beg valid: loop entered
                int2 e = es[src];
                vv[j] = idx < end ? __int_as_float(e.y) : 0.f;
                xx[j] = in8[(size_t)e.x * 256 + sc];
            }
#pragma unroll
            for (int j = 0; j < 8; j++) {
                float4* ap = (j & 1) ? &a1 : &a0;
                ap->x += vv[j] * bf2f((unsigned short)xx[j]);
                ap->y += vv[j] * bf2f((unsigned short)(xx[j] >> 16));
                ap->z += vv[j] * bf2f((unsigned short)(xx[j] >> 32));
                ap->w += vv[j] * bf2f((unsigned short)(xx[j] >> 48));
            }
        }

        float4 acc;
        acc.x = a0.x + a1.x;
        acc.y = a0.y + a1.y;
        acc.z = a0.z + a1.z;
        acc.w = a0.w + a1.w;
        acc.x += __shfl_xor(acc.x, 32);
        acc.y += __shfl_xor(acc.y, 32);
        acc.z += __shfl_xor(acc.z, 32);
        acc.w += __shfl_xor(acc.w, 32);

        if (ep == 0) {
            float o0, o1, o2, o3;
            if (has_sub) {
                o0 = scale * acc.x - bf2f((unsigned short)sv);
                o1 = scale * acc.y - bf2f((unsigned short)(sv >> 16));
                o2 = scale * acc.z - bf2f((unsigned short)(sv >> 32));
                o3 = scale * acc.w - bf2f((unsigned short)(sv >> 48));
            } else {
                o0 = acc.x; o1 = acc.y; o2 = acc.z; o3 = acc.w;
            }
            ((u64*)out)[oi] = pack4(o0, o1, o2, o3);   // normal store: keep in L2
        }
    }
}

// ---------------- MFMA GEMM + bias + ReLU + maxpool ----------------
// One wave = one (batch b, 16-node tile). D row = quad*4+r -> lane's 4 acc rows
// are exactly one pool group; ReLU+maxpool collapse to in-lane max. No LDS.

__global__ __launch_bounds__(256) void gemm_mfma_pool_kernel(
        const unsigned short* __restrict__ tbase, const unsigned short* __restrict__ WB,
        const float* __restrict__ bias, float* __restrict__ out) {
    int gtid = blockIdx.x * 256 + threadIdx.x;
    int lane = threadIdx.x & 63;
    int wid  = gtid >> 6;            // [0, 8192)
    int b    = wid >> 8;             // [0, 32)
    int n0   = (wid & 255) << 4;     // node tile base
    int m    = lane & 15;
    int q    = lane >> 4;

    f32x4 acc[4] = {{0.f,0.f,0.f,0.f},{0.f,0.f,0.f,0.f},
                    {0.f,0.f,0.f,0.f},{0.f,0.f,0.f,0.f}};

    const unsigned short* abase = tbase + (size_t)(n0 + m) * BC + b * CIN + q * 8;
    const unsigned short* wbase = WB + m * 32 + q * 8;

#pragma unroll
    for (int k = 0; k < KDEG; k++) {
        s16x8 a = *(const s16x8*)(abase + (size_t)k * TBF);
#pragma unroll
        for (int ot = 0; ot < 4; ot++) {
            s16x8 bf = *(const s16x8*)(wbase + ((k * 64) + ot * 16) * 32);
            acc[ot] = __builtin_amdgcn_mfma_f32_16x16x32_bf16(a, bf, acc[ot], 0, 0, 0);
        }
    }

    size_t orow = ((size_t)b * (NNODE / POOL) + (n0 >> 2) + q) * COUT;
#pragma unroll
    for (int ot = 0; ot < 4; ot++) {
        float bi = bias[ot * 16 + m];
        float r0 = acc[ot][0] + bi; r0 = r0 > 0.f ? r0 : 0.f;
        float r1 = acc[ot][1] + bi; r1 = r1 > 0.f ? r1 : 0.f;
        float r2 = acc[ot][2] + bi; r2 = r2 > 0.f ? r2 : 0.f;
        float r3 = acc[ot][3] + bi; r3 = r3 > 0.f ? r3 : 0.f;
        float mx = r0 > r1 ? r0 : r1;
        mx = mx > r2 ? mx : r2;
        mx = mx > r3 ? mx : r3;
        out[orow + ot * 16 + m] = mx;
    }
}

// ---------------- launch ----------------

extern "C" void kernel_launch(void* const* d_in, const int* in_sizes, int n_in,
                              void* d_out, int out_size, void* d_ws, size_t ws_size,
                              hipStream_t stream) {
    const float* x    = (const float*)d_in[0];
    const float* eval = (const float*)d_in[1];
    const float* W    = (const float*)d_in[2];
    const float* bias = (const float*)d_in[3];
    const int*   erow = (const int*)d_in[4];
    const int*   ecol = (const int*)d_in[5];
    float* out = (float*)d_out;

    char* base = (char*)d_ws;
    unsigned short* tb = (unsigned short*)base;     // 5 levels x 8 MB (bf16)
    unsigned short* t0 = tb;
    unsigned short* t1 = tb + 1 * TBF;
    unsigned short* t2 = tb + 2 * TBF;
    unsigned short* t3 = tb + 3 * TBF;
    unsigned short* t4 = tb + 4 * TBF;

    size_t off = 5 * TBF * sizeof(unsigned short);
    int2* es       = (int2*)(base + off);  off += (size_t)NNZ_E * sizeof(int2);
    int* row_start = (int*)(base + off);   off += (size_t)(NNODE + 1) * sizeof(int);
    off = (off + 63) & ~(size_t)63;
    unsigned short* WB = (unsigned short*)(base + off);

    // transpose + W pack; CSR build (single kernel, d_ws re-poisoned every call)
    prep_kernel<<<TBF / 4 / 256, 256, 0, stream>>>(x, t0, W, WB);
    csr_build_kernel<<<1, 1024, 0, stream>>>(erow, ecol, eval, es, row_start);

    // Chebyshev recursion: strip-mined, column-sliced, bf16 / fp32 accumulate
    spmm_cheb_strip_kernel<<<2048, 256, 0, stream>>>(t0, nullptr, t1, 1.0f, 0,
                                                     row_start, es);
    spmm_cheb_strip_kernel<<<2048, 256, 0, stream>>>(t1, t0, t2, 2.0f, 1,
                                                     row_start, es);
    spmm_cheb_strip_kernel<<<2048, 256, 0, stream>>>(t2, t1, t3, 2.0f, 1,
                                                     row_start, es);
    spmm_cheb_strip_kernel<<<2048, 256, 0, stream>>>(t3, t2, t4, 2.0f, 1,
                                                     row_start, es);

    // MFMA GEMM + bias + relu + maxpool (bf16 inputs, fp32 accumulate)
    gemm_mfma_pool_kernel<<<(BATCH * (NNODE / 16) * 64) / 256, 256, 0, stream>>>(
        tb, WB, bias, out);
}

// Round 8
// 222.185 us; speedup vs baseline: 1.3256x; 1.3256x over previous
//
#include <hip/hip_runtime.h>
#include <hip/hip_bf16.h>

// Problem constants
#define BATCH 32
#define NNODE 4096
#define CIN 32
#define COUT 64
#define KDEG 5
#define POOL 4
#define NNZ_E 65536
#define BC (BATCH * CIN)         // 1024 elems per node-row
#define TBF ((size_t)NNODE * BC) // elems per Chebyshev level (bf16 storage)

typedef short s16x8 __attribute__((ext_vector_type(8)));
typedef float f32x4 __attribute__((ext_vector_type(4)));
typedef unsigned long long u64;

// float -> bf16 bits, round-to-nearest-even
__device__ __forceinline__ unsigned short f2bf(float f) {
    union { float f; unsigned int u; } v; v.f = f;
    unsigned int u = v.u;
    u += 0x7fffu + ((u >> 16) & 1u);
    return (unsigned short)(u >> 16);
}
__device__ __forceinline__ float bf2f(unsigned short b) {
    union { float f; unsigned int u; } v; v.u = ((unsigned int)b) << 16;
    return v.f;
}
__device__ __forceinline__ u64 pack4(float a, float b, float c, float d) {
    return (u64)f2bf(a) | ((u64)f2bf(b) << 16) | ((u64)f2bf(c) << 32) | ((u64)f2bf(d) << 48);
}

// ---------------- prep: transpose x -> t0 (bf16), edge histogram, pack W --------

__global__ void prep_kernel(const float* __restrict__ x, unsigned short* __restrict__ t0,
                            const int* __restrict__ erow, int* __restrict__ cnt,
                            const float* __restrict__ W, unsigned short* __restrict__ WB) {
    int idx = blockIdx.x * 256 + threadIdx.x;   // [0, 1048576)
    int n   = idx >> 8;
    int rem = idx & 255;
    int b   = rem >> 3;
    int c4  = rem & 7;
    float4 v = ((const float4*)x)[(b * NNODE + n) * 8 + c4];
    ((u64*)t0)[idx] = pack4(v.x, v.y, v.z, v.w);

    if (idx < NNZ_E) atomicAdd(&cnt[erow[idx]], 1);

    if (idx < KDEG * COUT * CIN) {
        int c = idx & 31;
        int rest = idx >> 5;
        int o = rest & 63;
        int k = rest >> 6;
        // WB[k][o][c] : B-fragment order for mfma_16x16x32 (lane nn=o, kk=c)
        WB[idx] = f2bf(W[(c * KDEG + k) * COUT + o]);
    }
}

// ---------------- scan: cnt -> row_start / cursor ----------------

__global__ void scan_kernel(const int* __restrict__ cnt, int* __restrict__ row_start,
                            int* __restrict__ cursor) {
    __shared__ int sums[256];
    int tid = threadIdx.x;
    int local[16];
    int s = 0;
#pragma unroll
    for (int i = 0; i < 16; i++) { local[i] = cnt[tid * 16 + i]; s += local[i]; }
    sums[tid] = s;
    __syncthreads();
    for (int off = 1; off < 256; off <<= 1) {
        int v = 0;
        if (tid >= off) v = sums[tid - off];
        __syncthreads();
        if (tid >= off) sums[tid] += v;
        __syncthreads();
    }
    int base = sums[tid] - s;
    int run = base;
#pragma unroll
    for (int i = 0; i < 16; i++) {
        int r = tid * 16 + i;
        row_start[r] = run;
        cursor[r] = run;
        run += local[i];
    }
    if (tid == 255) row_start[NNODE] = sums[255];
}

// ---------------- scatter edges row-sorted as (col, val_bits) pairs ----------------

__global__ void scatter_kernel(const int* __restrict__ erow, const int* __restrict__ ecol,
                               const float* __restrict__ eval, int* __restrict__ cursor,
                               int2* __restrict__ es) {
    int e = blockIdx.x * blockDim.x + threadIdx.x;
    if (e < NNZ_E) {
        int pos = atomicAdd(&cursor[erow[e]], 1);
        es[pos] = make_int2(ecol[e], __float_as_int(eval[e]));
    }
}

// ---------------- strip-mined column-sliced bf16 SpMM: out = scale*(L@in) - sub ----
// Wave = (slice, 4-row strip). Slice = 128 cols (1 MB) pinned to XCD via blockIdx&7.
// Per row: sub prefetched first (hidden), 16 edges/iter (2 ep-groups x 8-deep).
// Prologue (row_start) amortized over 4 rows. Normal out-store keeps slice in L2.

__global__ __launch_bounds__(256) void spmm_cheb_strip_kernel(
        const unsigned short* __restrict__ in, const unsigned short* __restrict__ sub,
        unsigned short* __restrict__ out, float scale, int has_sub,
        const int* __restrict__ row_start, const int2* __restrict__ es) {
    int bx    = blockIdx.x;            // [0, 2048)
    int slice = bx & 7;                // XCD-matched column slice
    int w     = threadIdx.x >> 6;
    int strip = (bx >> 3) * 4 + w;     // [0, 1024)
    int r0    = strip * 4;
    int lane  = threadIdx.x & 63;
    int ep    = lane >> 5;             // edge-parallel half 0..1
    int c     = lane & 31;             // u64 col within slice
    int sc    = slice * 32 + c;        // absolute u64 col (256 per row)

    const u64* in8 = (const u64*)in;

    int rs[5];
#pragma unroll
    for (int j = 0; j < 5; j++) rs[j] = row_start[r0 + j];

#pragma unroll
    for (int rr = 0; rr < 4; rr++) {
        int r = r0 + rr;
        int beg = rs[rr], end = rs[rr + 1];
        size_t oi = (size_t)r * 256 + sc;
        u64 sv = 0;
        if (has_sub) sv = __builtin_nontemporal_load((const u64*)sub + oi);  // early

        float4 a0 = make_float4(0.f, 0.f, 0.f, 0.f);
        float4 a1 = a0;

        for (int base = beg + ep; base < end; base += 16) {
            float vv[8];
            u64   xx[8];
#pragma unroll
            for (int j = 0; j < 8; j++) {
                int idx = base + 2 * j;
                int src = idx < end ? idx : beg;   // beg valid: loop entered
                int2 e = es[src];
                vv[j] = idx < end ? __int_as_float(e.y) : 0.f;
                xx[j] = in8[(size_t)e.x * 256 + sc];
            }
#pragma unroll
            for (int j = 0; j < 8; j++) {
                float4* ap = (j & 1) ? &a1 : &a0;
                ap->x += vv[j] * bf2f((unsigned short)xx[j]);
                ap->y += vv[j] * bf2f((unsigned short)(xx[j] >> 16));
                ap->z += vv[j] * bf2f((unsigned short)(xx[j] >> 32));
                ap->w += vv[j] * bf2f((unsigned short)(xx[j] >> 48));
            }
        }

        float4 acc;
        acc.x = a0.x + a1.x;
        acc.y = a0.y + a1.y;
        acc.z = a0.z + a1.z;
        acc.w = a0.w + a1.w;
        acc.x += __shfl_xor(acc.x, 32);
        acc.y += __shfl_xor(acc.y, 32);
        acc.z += __shfl_xor(acc.z, 32);
        acc.w += __shfl_xor(acc.w, 32);

        if (ep == 0) {
            float o0, o1, o2, o3;
            if (has_sub) {
                o0 = scale * acc.x - bf2f((unsigned short)sv);
                o1 = scale * acc.y - bf2f((unsigned short)(sv >> 16));
                o2 = scale * acc.z - bf2f((unsigned short)(sv >> 32));
                o3 = scale * acc.w - bf2f((unsigned short)(sv >> 48));
            } else {
                o0 = acc.x; o1 = acc.y; o2 = acc.z; o3 = acc.w;
            }
            ((u64*)out)[oi] = pack4(o0, o1, o2, o3);   // normal store: keep in L2
        }
    }
}

// ---------------- MFMA GEMM + bias + ReLU + maxpool ----------------
// One wave = one (batch b, 16-node tile). D row = quad*4+r -> lane's 4 acc rows
// are exactly one pool group; ReLU+maxpool collapse to in-lane max. No LDS.

__global__ __launch_bounds__(256) void gemm_mfma_pool_kernel(
        const unsigned short* __restrict__ tbase, const unsigned short* __restrict__ WB,
        const float* __restrict__ bias, float* __restrict__ out) {
    int gtid = blockIdx.x * 256 + threadIdx.x;
    int lane = threadIdx.x & 63;
    int wid  = gtid >> 6;            // [0, 8192)
    int b    = wid >> 8;             // [0, 32)
    int n0   = (wid & 255) << 4;     // node tile base
    int m    = lane & 15;
    int q    = lane >> 4;

    f32x4 acc[4] = {{0.f,0.f,0.f,0.f},{0.f,0.f,0.f,0.f},
                    {0.f,0.f,0.f,0.f},{0.f,0.f,0.f,0.f}};

    const unsigned short* abase = tbase + (size_t)(n0 + m) * BC + b * CIN + q * 8;
    const unsigned short* wbase = WB + m * 32 + q * 8;

#pragma unroll
    for (int k = 0; k < KDEG; k++) {
        s16x8 a = *(const s16x8*)(abase + (size_t)k * TBF);
#pragma unroll
        for (int ot = 0; ot < 4; ot++) {
            s16x8 bf = *(const s16x8*)(wbase + ((k * 64) + ot * 16) * 32);
            acc[ot] = __builtin_amdgcn_mfma_f32_16x16x32_bf16(a, bf, acc[ot], 0, 0, 0);
        }
    }

    size_t orow = ((size_t)b * (NNODE / POOL) + (n0 >> 2) + q) * COUT;
#pragma unroll
    for (int ot = 0; ot < 4; ot++) {
        float bi = bias[ot * 16 + m];
        float r0 = acc[ot][0] + bi; r0 = r0 > 0.f ? r0 : 0.f;
        float r1 = acc[ot][1] + bi; r1 = r1 > 0.f ? r1 : 0.f;
        float r2 = acc[ot][2] + bi; r2 = r2 > 0.f ? r2 : 0.f;
        float r3 = acc[ot][3] + bi; r3 = r3 > 0.f ? r3 : 0.f;
        float mx = r0 > r1 ? r0 : r1;
        mx = mx > r2 ? mx : r2;
        mx = mx > r3 ? mx : r3;
        out[orow + ot * 16 + m] = mx;
    }
}

// ---------------- launch ----------------

extern "C" void kernel_launch(void* const* d_in, const int* in_sizes, int n_in,
                              void* d_out, int out_size, void* d_ws, size_t ws_size,
                              hipStream_t stream) {
    const float* x    = (const float*)d_in[0];
    const float* eval = (const float*)d_in[1];
    const float* W    = (const float*)d_in[2];
    const float* bias = (const float*)d_in[3];
    const int*   erow = (const int*)d_in[4];
    const int*   ecol = (const int*)d_in[5];
    float* out = (float*)d_out;

    char* base = (char*)d_ws;
    unsigned short* tb = (unsigned short*)base;     // 5 levels x 8 MB (bf16)
    unsigned short* t0 = tb;
    unsigned short* t1 = tb + 1 * TBF;
    unsigned short* t2 = tb + 2 * TBF;
    unsigned short* t3 = tb + 3 * TBF;
    unsigned short* t4 = tb + 4 * TBF;

    size_t off = 5 * TBF * sizeof(unsigned short);
    int2* es       = (int2*)(base + off);  off += (size_t)NNZ_E * sizeof(int2);
    int* cnt       = (int*)(base + off);   off += (size_t)NNODE * sizeof(int);
    int* row_start = (int*)(base + off);   off += (size_t)(NNODE + 1) * sizeof(int);
    int* cursor    = (int*)(base + off);   off += (size_t)NNODE * sizeof(int);
    off = (off + 63) & ~(size_t)63;
    unsigned short* WB = (unsigned short*)(base + off);

    // parallel CSR build + transpose + W pack (d_ws re-poisoned -> rebuild each call)
    hipMemsetAsync(cnt, 0, NNODE * sizeof(int), stream);
    prep_kernel<<<TBF / 4 / 256, 256, 0, stream>>>(x, t0, erow, cnt, W, WB);
    scan_kernel<<<1, 256, 0, stream>>>(cnt, row_start, cursor);
    scatter_kernel<<<NNZ_E / 256, 256, 0, stream>>>(erow, ecol, eval, cursor, es);

    // Chebyshev recursion: strip-mined, column-sliced, bf16 / fp32 accumulate
    spmm_cheb_strip_kernel<<<2048, 256, 0, stream>>>(t0, nullptr, t1, 1.0f, 0,
                                                     row_start, es);
    spmm_cheb_strip_kernel<<<2048, 256, 0, stream>>>(t1, t0, t2, 2.0f, 1,
                                                     row_start, es);
    spmm_cheb_strip_kernel<<<2048, 256, 0, stream>>>(t2, t1, t3, 2.0f, 1,
                                                     row_start, es);
    spmm_cheb_strip_kernel<<<2048, 256, 0, stream>>>(t3, t2, t4, 2.0f, 1,
                                                     row_start, es);

    // MFMA GEMM + bias + relu + maxpool (bf16 inputs, fp32 accumulate)
    gemm_mfma_pool_kernel<<<(BATCH * (NNODE / 16) * 64) / 256, 256, 0, stream>>>(
        tb, WB, bias, out);
}